// Round 1
// 432.206 us; speedup vs baseline: 1.0460x; 1.0460x over previous
//
#include <hip/hip_runtime.h>
#include <cstdint>
#include <cstddef>

typedef unsigned short u16;
using f16x8 = __attribute__((ext_vector_type(8))) _Float16;
using f32x4 = __attribute__((ext_vector_type(4))) float;
using u16x4 = __attribute__((ext_vector_type(4))) unsigned short;

// float -> fp16 bit pattern (round-to-nearest-even via v_cvt_f16_f32)
__device__ __forceinline__ u16 f2h(float f) {
  union { _Float16 h; u16 u; } c;
  c.h = (_Float16)f;
  return c.u;
}

// async global->LDS, 16B per lane. LDS dest must be wave-uniform base; HW writes base + lane*16.
__device__ __forceinline__ void gl_lds16(const void* g, void* lds) {
  __builtin_amdgcn_global_load_lds(
      (const __attribute__((address_space(1))) void*)(uintptr_t)g,
      (__attribute__((address_space(3))) void*)(uint32_t)(uintptr_t)lds,
      16, 0, 0);
}

// Stage a ROWS x 64 u16 tile (row-major [ROWS][64] in LDS) from g (leading dim ldk u16).
// 512 threads, 16B/lane/issue; slot s = 16B chunk: row = s>>3, chunk = s&7.
// LDS dest is wave-uniform (slot base with lane zeroed) per global_load_lds semantics.
template <int ROWS>
__device__ __forceinline__ void stage_tile(const u16* g, int ldk, u16* lds, int t) {
#pragma unroll
  for (int i = 0; i < ROWS / 64; ++i) {
    const int s = i * 512 + t;
    gl_lds16(g + (size_t)(s >> 3) * ldk + (s & 7) * 8,
             lds + (size_t)(i * 512 + (t & ~63)) * 8);
  }
}

// ---------------------------------------------------------------------------
// bt-GEMM, 256 x BN tile, BK=64, 8 waves (2M x 4N), double-buffered LDS,
// single-barrier overlapped 2-phase schedule (T3 minimum recipe):
//   STAGE(next tile) -> ds_read+MFMA(current) -> __syncthreads (vmcnt0+barrier)
// so the global_load_lds latency hides under the MFMA phase.
// C[m,n] = sum_k A[m,k]*Bt[n,k]. A:[M,K] fp16 rm, Bt:[Ncols,K] fp16 rm.
// MODE 0: fp16 out (+bias). MODE 1: fp32 out. MODE 2: fp32 elu out.
// Requires M%256==0, Ncols%BN==0, K%64==0.
// ---------------------------------------------------------------------------
template <int BN, int MODE>
__global__ __launch_bounds__(512) void gemm256(
    const u16* __restrict__ A, const u16* __restrict__ Bt,
    void* __restrict__ Cv, const float* __restrict__ bias,
    int M, int Ncols, int K,
    long long strideA, long long strideB, long long strideC)
{
  constexpr int NF = BN / 64;  // 16x16 frags per wave in N: BN=256 -> 4, BN=128 -> 2
  __shared__ __align__(16) u16 sA[2][256 * 64];
  __shared__ __align__(16) u16 sB[2][BN * 64];

  const int bz = blockIdx.z;
  A  += (size_t)bz * strideA;
  Bt += (size_t)bz * strideB;

  const int m0 = blockIdx.y * 256;
  const int n0 = blockIdx.x * BN;
  const int t    = threadIdx.x;
  const int lane = t & 63;
  const int wave = t >> 6;
  const int wm   = (wave >> 2) * 128;       // 2 waves in M, 128 rows each
  const int wn   = (wave & 3) * (BN / 4);   // 4 waves in N
  const int lm   = lane & 15;
  const int quad = lane >> 4;

  f32x4 acc[8][NF];
#pragma unroll
  for (int i = 0; i < 8; ++i)
#pragma unroll
    for (int j = 0; j < NF; ++j) acc[i][j] = f32x4{0.f, 0.f, 0.f, 0.f};

  const u16* Ag = A + (size_t)m0 * K;
  const u16* Bg = Bt + (size_t)n0 * K;

  const int nk = K >> 6;
  stage_tile<256>(Ag, K, sA[0], t);
  stage_tile<BN >(Bg, K, sB[0], t);
  __syncthreads();  // vmcnt(0) drain + barrier: buf0 ready

  for (int kt = 0; kt < nk; ++kt) {
    const int cur = kt & 1;
    if (kt + 1 < nk) {  // prefetch next K-tile into other buffer; overlaps MFMA below
      stage_tile<256>(Ag + ((kt + 1) << 6), K, sA[cur ^ 1], t);
      stage_tile<BN >(Bg + ((kt + 1) << 6), K, sB[cur ^ 1], t);
    }

    const u16* pA = sA[cur];
    const u16* pB = sB[cur];
    f16x8 bf[NF][2];
#pragma unroll
    for (int nf = 0; nf < NF; ++nf)
#pragma unroll
      for (int ks = 0; ks < 2; ++ks)
        bf[nf][ks] = *(const f16x8*)(pB + (wn + nf * 16 + lm) * 64 + ks * 32 + quad * 8);
#pragma unroll
    for (int mf = 0; mf < 8; ++mf) {
      const u16* ra = pA + (wm + mf * 16 + lm) * 64 + quad * 8;
      f16x8 a0 = *(const f16x8*)(ra);
      f16x8 a1 = *(const f16x8*)(ra + 32);
#pragma unroll
      for (int nf = 0; nf < NF; ++nf) {
        acc[mf][nf] = __builtin_amdgcn_mfma_f32_16x16x32_f16(a0, bf[nf][0], acc[mf][nf], 0, 0, 0);
        acc[mf][nf] = __builtin_amdgcn_mfma_f32_16x16x32_f16(a1, bf[nf][1], acc[mf][nf], 0, 0, 0);
      }
    }
    if (kt + 1 < nk) __syncthreads();  // drains prefetch loads (already overlapped) + read/write fence
  }

  // epilogue: C/D layout col=lane&15, row=quad*4+reg  [m89-verified, dtype-independent]
  if (MODE == 0) {
    u16* C = (u16*)Cv + (size_t)bz * strideC;
#pragma unroll
    for (int nf = 0; nf < NF; ++nf) {
      const int col = n0 + wn + nf * 16 + lm;
      const float bv = bias ? bias[col] : 0.f;
#pragma unroll
      for (int mf = 0; mf < 8; ++mf)
#pragma unroll
        for (int r = 0; r < 4; ++r) {
          const int row = m0 + wm + mf * 16 + quad * 4 + r;
          C[(size_t)row * Ncols + col] = f2h(acc[mf][nf][r] + bv);
        }
    }
  } else {
    float* C = (float*)Cv + (size_t)bz * strideC;
#pragma unroll
    for (int nf = 0; nf < NF; ++nf) {
      const int col = n0 + wn + nf * 16 + lm;
#pragma unroll
      for (int mf = 0; mf < 8; ++mf)
#pragma unroll
        for (int r = 0; r < 4; ++r) {
          const int row = m0 + wm + mf * 16 + quad * 4 + r;
          float v = acc[mf][nf][r];
          if (MODE == 2) v = v > 0.f ? v : expm1f(v);
          C[(size_t)row * Ncols + col] = v;
        }
    }
  }
}

// ---------------------------------------------------------------------------
// masked softmax over one row of 2048: P = softmax(where(adj==0, -inf, S)), fp16 out
// ---------------------------------------------------------------------------
__global__ __launch_bounds__(256) void masked_softmax(
    const float* __restrict__ S, const int* __restrict__ adj, u16* __restrict__ P)
{
  const size_t row = blockIdx.x;
  const float* s = S + row * 2048;
  const int*   a = adj + row * 2048;
  u16*         p = P + row * 2048;
  const int t = threadIdx.x;

  float v[8];
#pragma unroll
  for (int i = 0; i < 2; ++i) {
    float4 sv = ((const float4*)s)[t + i * 256];
    int4   av = ((const int4*)a)[t + i * 256];
    v[i * 4 + 0] = av.x ? sv.x : -1e30f;
    v[i * 4 + 1] = av.y ? sv.y : -1e30f;
    v[i * 4 + 2] = av.z ? sv.z : -1e30f;
    v[i * 4 + 3] = av.w ? sv.w : -1e30f;
  }
  float mx = v[0];
#pragma unroll
  for (int i = 1; i < 8; ++i) mx = fmaxf(mx, v[i]);
#pragma unroll
  for (int o = 32; o > 0; o >>= 1) mx = fmaxf(mx, __shfl_xor(mx, o));
  __shared__ float red[4];
  if ((t & 63) == 0) red[t >> 6] = mx;
  __syncthreads();
  mx = fmaxf(fmaxf(red[0], red[1]), fmaxf(red[2], red[3]));
  __syncthreads();

  float e[8]; float sum = 0.f;
#pragma unroll
  for (int i = 0; i < 8; ++i) { e[i] = __expf(v[i] - mx); sum += e[i]; }
#pragma unroll
  for (int o = 32; o > 0; o >>= 1) sum += __shfl_xor(sum, o);
  if ((t & 63) == 0) red[t >> 6] = sum;
  __syncthreads();
  sum = red[0] + red[1] + red[2] + red[3];
  const float inv = 1.f / sum;

#pragma unroll
  for (int i = 0; i < 2; ++i) {
    u16x4 o4;
    o4[0] = f2h(e[i * 4 + 0] * inv);
    o4[1] = f2h(e[i * 4 + 1] * inv);
    o4[2] = f2h(e[i * 4 + 2] * inv);
    o4[3] = f2h(e[i * 4 + 3] * inv);
    ((u16x4*)p)[t + i * 256] = o4;
  }
}

// ---------------------------------------------------------------------------
// 16-bit transpose per batch (z): in [R][C] -> out [C][R], 64x64 LDS tiles
// ---------------------------------------------------------------------------
__global__ __launch_bounds__(256) void transpose_u16(
    const u16* __restrict__ in, u16* __restrict__ outp, int R, int C)
{
  __shared__ u16 tile[64][65];
  const size_t base = (size_t)blockIdx.z * R * C;
  const int r0 = blockIdx.y * 64, c0 = blockIdx.x * 64;
  const int t = threadIdx.x;
  const int c = t & 63, rr = t >> 6;
#pragma unroll
  for (int i = 0; i < 16; ++i) {
    const int r = rr + i * 4;
    tile[r][c] = in[base + (size_t)(r0 + r) * C + c0 + c];
  }
  __syncthreads();
  const int rp = t & 63, cc = t >> 6;
#pragma unroll
  for (int i = 0; i < 16; ++i) {
    const int cq = cc + i * 4;
    outp[base + (size_t)(c0 + cq) * R + r0 + rp] = tile[rp][cq];
  }
}

__global__ __launch_bounds__(256) void cvt_f32_f16(
    const float* __restrict__ in, u16* __restrict__ outp, int n4)
{
  const int i = blockIdx.x * 256 + threadIdx.x;
  if (i >= n4) return;
  float4 v = ((const float4*)in)[i];
  u16x4 o; o[0] = f2h(v.x); o[1] = f2h(v.y); o[2] = f2h(v.z); o[3] = f2h(v.w);
  ((u16x4*)outp)[i] = o;
}

// out[j*R + i] = fp16(in[i*C + j])  (coalesced reads, tiny matrix)
__global__ __launch_bounds__(256) void transpose_cvt(
    const float* __restrict__ in, u16* __restrict__ outp, int R, int C)
{
  const int idx = blockIdx.x * 256 + threadIdx.x;
  const int i = idx / C, j = idx % C;
  outp[(size_t)j * R + i] = f2h(in[idx]);
}

// ---------------------------------------------------------------------------
extern "C" void kernel_launch(void* const* d_in, const int* in_sizes, int n_in,
                              void* d_out, int out_size, void* d_ws, size_t ws_size,
                              hipStream_t stream) {
  (void)in_sizes; (void)n_in; (void)out_size;
  const float* x    = (const float*)d_in[0];
  const int*   adj  = (const int*)d_in[1];
  const float* W    = (const float*)d_in[2];
  const float* bvec = (const float*)d_in[3];
  const float* attn = (const float*)d_in[4];
  float* out = (float*)d_out;

  constexpr int B = 8, N = 2048, D = 512;
  constexpr size_t MN = (size_t)B * N;  // 16384

  char* ws = (char*)d_ws;
  size_t off = 0;
  auto take = [&](size_t bytes) -> char* {
    char* p = ws + off;
    off += (bytes + 255) & ~(size_t)255;
    return p;
  };
  u16* xh   = (u16*)take(MN * D * 2);
  u16* Wh   = (u16*)take((size_t)D * D * 2);
  u16* attT = (u16*)take((size_t)D * D * 2);
  u16* h    = (u16*)take(MN * D * 2);
  u16* hT   = (u16*)take(MN * D * 2);
  u16* ha   = (u16*)take(MN * D * 2);

  auto al = [](size_t b) { return (b + 255) & ~(size_t)255; };
  const size_t szSf = al((size_t)B * N * N * 4), szPf = al((size_t)B * N * N * 2);
  const size_t szSb = al((size_t)N * N * 4),     szPb = al((size_t)N * N * 2);
  const bool full  = ws_size >= off + szSf + szPf;
  const bool ok_pb = ws_size >= off + szSb + szPb;
  if (!full && !ok_pb) return;  // ws too small; fail validation cleanly

  // converts
  cvt_f32_f16<<<dim3((unsigned)(MN * D / 4 / 256)), 256, 0, stream>>>(x, xh, (int)(MN * D / 4));
  cvt_f32_f16<<<dim3(D * D / 4 / 256), 256, 0, stream>>>(W, Wh, D * D / 4);
  transpose_cvt<<<dim3(D * D / 256), 256, 0, stream>>>(attn, attT, D, D);

  // K1: h = xh . Wh^T + bias   [16384,512] x [512,512]  (256x128 tiles -> 256 blocks)
  gemm256<128, 0><<<dim3(D / 128, MN / 256, 1), 512, 0, stream>>>(
      xh, Wh, h, bvec, (int)MN, D, D, 0, 0, 0);
  // hT per batch: [2048,512] -> [512,2048]
  transpose_u16<<<dim3(D / 64, N / 64, B), 256, 0, stream>>>(h, hT, N, D);
  // K2: ha = h . attT^T
  gemm256<128, 0><<<dim3(D / 128, MN / 256, 1), 512, 0, stream>>>(
      h, attT, ha, nullptr, (int)MN, D, D, 0, 0, 0);

  if (full) {
    float* S = (float*)take(szSf);
    u16*   P = (u16*)take(szPf);
    // K3: S = ha . h^T per batch  (256x256 tiles -> 512 blocks)
    gemm256<256, 1><<<dim3(N / 256, N / 256, B), 512, 0, stream>>>(
        ha, h, S, nullptr, N, N, D,
        (long long)N * D, (long long)N * D, (long long)N * N);
    // K4: masked softmax -> P fp16
    masked_softmax<<<dim3((unsigned)(B * N)), 256, 0, stream>>>(S, adj, P);
    // K5: out = elu(P . hT^T) per batch  (256x128 tiles -> 256 blocks)
    gemm256<128, 2><<<dim3(D / 128, N / 256, B), 512, 0, stream>>>(
        P, hT, out, nullptr, N, D, N,
        (long long)N * N, (long long)D * N, (long long)N * D);
  } else {
    float* S = (float*)take(szSb);
    u16*   P = (u16*)take(szPb);
    for (int b = 0; b < B; ++b) {
      gemm256<256, 1><<<dim3(N / 256, N / 256, 1), 512, 0, stream>>>(
          ha + (size_t)b * N * D, h + (size_t)b * N * D, S, nullptr, N, N, D, 0, 0, 0);
      masked_softmax<<<dim3(N), 256, 0, stream>>>(S, adj + (size_t)b * N * N, P);
      gemm256<128, 2><<<dim3(D / 128, N / 256, 1), 512, 0, stream>>>(
          P, hT + (size_t)b * D * N, out + (size_t)b * N * D, nullptr, N, D, N, 0, 0, 0);
    }
  }
}